// Round 1
// baseline (434.905 us; speedup 1.0000x reference)
//
#include <hip/hip_runtime.h>
#include <hip/hip_bf16.h>
#include <cstdint>
#include <cstddef>

// LinOSS block: B=32, T=4096, H=256, S=256, M = B*T = 131072
// v4: 32-row tiles, wave tile 32m x 32n -> Wf = 64 VGPR, launch_bounds(512,4)
// targets <=128 VGPR => 4 waves/SIMD, 2 blocks/CU (grid 512).
// scan_carries fused into gemm<0> epilogue (register carry over Es tiles),
// scan_apply fused into gemm<1> staging (in-LDS u->states scan),
// gelu via exp-based sigmoid (no tanhf).

typedef __bf16 bf16x8 __attribute__((ext_vector_type(8)));
typedef __bf16 bf16x4 __attribute__((ext_vector_type(4)));
typedef float  f32x4  __attribute__((ext_vector_type(4)));
typedef unsigned int u32x4 __attribute__((ext_vector_type(4)));

#define BB 32
#define TT 4096
#define HH 256
#define SS 256
#define MTOT (BB*TT)          // 131072
#define NCHUNK 64             // chunks of 64 timesteps
#define NT 8                  // 32-row tiles per block -> 256 rows/block

// ---------------- prep: weight cast + coeff ----------------
__global__ void prep_kernel(const float* __restrict__ w1, const float* __restrict__ w2,
                            const float* __restrict__ w3,
                            __bf16* __restrict__ w1b, __bf16* __restrict__ w2b,
                            __bf16* __restrict__ w3b,
                            const float* __restrict__ a_diag, const float* __restrict__ g_diag,
                            const float* __restrict__ dt,
                            float* __restrict__ coeff, float* __restrict__ cL) {
    int i = blockIdx.x * 256 + threadIdx.x;   // 65536 threads = one per weight elem
    w1b[i] = (__bf16)w1[i];
    w2b[i] = (__bf16)w2[i];
    w3b[i] = (__bf16)w3[i];
    if (i < SS) {
        float d = dt[i];
        float sp = (d > 20.f) ? d : log1pf(expf(d));      // softplus
        float dts = sp + 1e-4f;
        float omega = a_diag[i] * dts;
        float gg = g_diag[i];
        float spg = (gg > 20.f) ? gg : log1pf(expf(gg));
        float dec = expf(-spg * dts);
        float c = dec * dec * cosf(omega);
        coeff[i] = c;
        float p = c;
        #pragma unroll
        for (int q = 0; q < 6; ++q) p = p * p;            // c^64
        cL[i] = p;
    }
}

// ---------------- LayerNorm ----------------
__global__ __launch_bounds__(256) void ln_kernel(const float* __restrict__ x,
                          const float* __restrict__ w, const float* __restrict__ b,
                          __bf16* __restrict__ xn) {
    int row = blockIdx.x * 4 + (threadIdx.x >> 6);
    int lane = threadIdx.x & 63;
    size_t base = (size_t)row * HH + lane * 4;
    const float4 v = *(const float4*)&x[base];
    float s  = v.x + v.y + v.z + v.w;
    float ss = v.x*v.x + v.y*v.y + v.z*v.z + v.w*v.w;
    #pragma unroll
    for (int off = 32; off; off >>= 1) {
        s  += __shfl_xor(s,  off, 64);
        ss += __shfl_xor(ss, off, 64);
    }
    float mu  = s * (1.f/256.f);
    float var = ss * (1.f/256.f) - mu*mu;
    float sc  = rsqrtf(var + 1e-5f);
    const float4 wv = *(const float4*)&w[lane*4];
    const float4 bv = *(const float4*)&b[lane*4];
    union { __bf16 h[4]; uint2 u; } pk;
    pk.h[0] = (__bf16)((v.x - mu)*sc*wv.x + bv.x);
    pk.h[1] = (__bf16)((v.y - mu)*sc*wv.y + bv.y);
    pk.h[2] = (__bf16)((v.z - mu)*sc*wv.z + bv.z);
    pk.h[3] = (__bf16)((v.w - mu)*sc*wv.w + bv.w);
    *(uint2*)&xn[base] = pk.u;
}

// in-LDS scan of one 32x256 bf16 tile (u -> states), column s = tid, 16B-granule
// swizzle g^(m&15). Serial over rows, batched 8 (independent reads, dep fma chain).
__device__ __forceinline__ void scan_xs_tile(__bf16* Xs, int tid, float c, float& st) {
    const int gb = tid >> 3, bo = (tid & 7) << 1;
    #pragma unroll
    for (int g4 = 0; g4 < 4; ++g4) {
        float v[8];
        #pragma unroll
        for (int r = 0; r < 8; ++r) {
            const int m = g4 * 8 + r;
            v[r] = (float)*(const __bf16*)((const char*)Xs + m * 512 + (((gb ^ (m & 15)) << 4) | bo));
        }
        __bf16 w[8];
        #pragma unroll
        for (int r = 0; r < 8; ++r) { st = c * st + v[r]; w[r] = (__bf16)st; }
        #pragma unroll
        for (int r = 0; r < 8; ++r) {
            const int m = g4 * 8 + r;
            *(__bf16*)((char*)Xs + m * 512 + (((gb ^ (m & 15)) << 4) | bo)) = w[r];
        }
    }
}

// read-only carry scan of one 32x256 Es tile (8B-granule swizzle gn^((m&15)<<2))
__device__ __forceinline__ void scan_es_carry(const __bf16* Es, int tid, float c, float& st) {
    const int gb = tid >> 2, bo = (tid & 3) << 1;
    #pragma unroll
    for (int g4 = 0; g4 < 4; ++g4) {
        float v[8];
        #pragma unroll
        for (int r = 0; r < 8; ++r) {
            const int m = g4 * 8 + r;
            v[r] = (float)*(const __bf16*)((const char*)Es + m * 512 + (((gb ^ ((m & 15) << 2)) << 3) | bo));
        }
        #pragma unroll
        for (int r = 0; r < 8; ++r) st = c * st + v[r];
    }
}

// ---------------- GEMM v4 ----------------
// C[m,n] = sum_k X[m,k] * W[n,k], M=131072, N=K=256.
// Block: 512 threads = 8 waves, each wave owns a 32n slice (full 32m of tile).
// Tile: 32 rows. Wf[2][8] = 64 VGPR. Xs/Es 16KB each (swizzled as in v3).
// MODE0: writes u + fused per-chunk carries. MODE1: fused u->states scan in LDS,
// then W2 GEMM + direct*xn + fast gelu. MODE2: out proj + residual + bias.
template<int MODE>
__global__ __launch_bounds__(512, 4) void gemm_kernel(
    const __bf16* __restrict__ W,   // [256][256] row-major (n x k)
    const __bf16* __restrict__ X,   // [M][256]
    void* Cout,                     // MODE0: bf16 u; MODE1: bf16 mixed (aliases xn_in); MODE2: f32 y
    const __bf16* xn_in,            // MODE1: x_norm (same buffer as Cout)
    const float* __restrict__ dvec, // MODE1: direct[H]
    const float* __restrict__ xres, // MODE2: x
    const float* __restrict__ bias, // MODE2: out_b
    const float* __restrict__ coeff,// MODE0/1: recurrence coeff[S]
    const float* __restrict__ state0,// MODE0/1: [B,S]
    float* carry)                   // MODE0: write local carries; MODE1: read prefix carries
{
    __shared__ __bf16 Xs[32 * 256];   // 16 KB, 16B-granule swizzle g^(m&15)
    __shared__ __bf16 Es[32 * 256];   // 16 KB, 8B-granule swizzle gn^((m&15)<<2)

    const int tid  = threadIdx.x;
    const int lane = tid & 63;
    const int wid  = tid >> 6;          // 0..7 = n-group of 32
    const int l15  = lane & 15, quad = lane >> 4;

    // ---- W fragments: wave's 32n slice, all k. 16 frags = 64 VGPR ----
    bf16x8 Wf[2][8];
    #pragma unroll
    for (int jn = 0; jn < 2; ++jn) {
        const int n = wid * 32 + jn * 16 + l15;
        #pragma unroll
        for (int kb = 0; kb < 8; ++kb)
            Wf[jn][kb] = *(const bf16x8*)&W[(size_t)n * 256 + kb * 32 + quad * 8];
    }

    // ---- scan preloads (chunk = 64 rows = 2 tiles; block = 4 chunks) ----
    const int bxi = blockIdx.x;
    const int bb  = bxi >> 4;           // batch
    const int chb = (bxi & 15) * 4;     // first chunk of this block (within batch)
    float c_s = 0.f, s0v = 0.f, cin0 = 0.f, cin1 = 0.f, cin2 = 0.f, cin3 = 0.f;
    if constexpr (MODE == 0) {
        if (tid < 256) {
            c_s = coeff[tid];
            if (chb == 0) s0v = state0[(size_t)bb * 256 + tid];
        }
    }
    if constexpr (MODE == 1) {
        if (tid < 256) {
            c_s = coeff[tid];
            cin0 = (chb == 0) ? state0[(size_t)bb * 256 + tid]
                              : carry[((size_t)bb * 64 + chb - 1) * 256 + tid];
            cin1 = carry[((size_t)bb * 64 + chb + 0) * 256 + tid];
            cin2 = carry[((size_t)bb * 64 + chb + 1) * 256 + tid];
            cin3 = carry[((size_t)bb * 64 + chb + 2) * 256 + tid];
        }
    }

    // ---- staging geometry: 2 x 16B granules per thread, wave-contiguous ----
    int sdst[2], srow[2];
    const int g = tid & 31;
    #pragma unroll
    for (int j = 0; j < 2; ++j) {
        const int m = j * 16 + (tid >> 5);
        srow[j] = m;
        sdst[j] = m * 512 + ((g ^ (m & 15)) * 16);
    }
    const int colb = g * 16;

    const size_t mbase = (size_t)bxi * 256;
    const char* Xb = (const char*)X;

    u32x4 pf[2];
    // stage tile 0
    #pragma unroll
    for (int j = 0; j < 2; ++j)
        pf[j] = *(const u32x4*)(Xb + (mbase + srow[j]) * 512 + colb);
    #pragma unroll
    for (int j = 0; j < 2; ++j)
        *(u32x4*)((char*)Xs + sdst[j]) = pf[j];
    __syncthreads();
    // prefetch tile 1
    #pragma unroll
    for (int j = 0; j < 2; ++j)
        pf[j] = *(const u32x4*)(Xb + (mbase + 32 + srow[j]) * 512 + colb);

    float st  = 0.f;   // MODE1 running state
    float stc = 0.f;   // MODE0 running carry
    if constexpr (MODE == 1) {
        if (tid < 256) { st = cin0; scan_xs_tile(Xs, tid, c_s, st); }
        __syncthreads();   // states of tile 0 visible before MFMA
    }

    const int hrow = tid >> 5;   // 0..15 epilogue row-in-group
    const int nc   = tid & 31;   // 16B chunk within row

    for (int it = 0; it < NT; ++it) {
        const size_t mt0 = mbase + (size_t)it * 32;

        // ---- MFMA phase on tile it ----
        f32x4 acc[2][2] = {};
        #pragma unroll
        for (int kb = 0; kb < 8; ++kb) {
            bf16x8 xf[2];
            #pragma unroll
            for (int im = 0; im < 2; ++im)
                xf[im] = *(const bf16x8*)((const char*)Xs + (l15 + im * 16) * 512
                                          + (((kb * 4 + quad) ^ l15) * 16));
            #pragma unroll
            for (int jn = 0; jn < 2; ++jn)
                #pragma unroll
                for (int im = 0; im < 2; ++im)
                    acc[im][jn] = __builtin_amdgcn_mfma_f32_16x16x32_bf16(
                        Wf[jn][kb], xf[im], acc[im][jn], 0, 0, 0);
        }
        __syncthreads();   // A: Xs reads done

        // ---- write next tile into Xs; dump acc into Es (bf16) ----
        if (it + 1 < NT) {
            #pragma unroll
            for (int j = 0; j < 2; ++j)
                *(u32x4*)((char*)Xs + sdst[j]) = pf[j];
        }
        #pragma unroll
        for (int im = 0; im < 2; ++im) {
            const int m = l15 + im * 16;
            #pragma unroll
            for (int jn = 0; jn < 2; ++jn) {
                const int gn = wid * 8 + jn * 4 + quad;     // 8B granule (= n>>2)
                bf16x4 pk;
                #pragma unroll
                for (int r = 0; r < 4; ++r) pk[r] = (__bf16)acc[im][jn][r];
                *(bf16x4*)((char*)Es + m * 512 + ((gn ^ (l15 << 2)) * 8)) = pk;
            }
        }
        __syncthreads();   // E: Es + Xs(it+1) ready

        // ---- prefetch tile it+2 ----
        if (it + 2 < NT) {
            #pragma unroll
            for (int j = 0; j < 2; ++j)
                pf[j] = *(const u32x4*)(Xb + (mt0 + 64 + srow[j]) * 512 + colb);
        }

        // ---- MODE1: u -> states scan of tile it+1 (in LDS, before next MFMA) ----
        if constexpr (MODE == 1) {
            if (it + 1 < NT && tid < 256) {
                const int itt = it + 1;
                if ((itt & 1) == 0) {                 // new chunk starts
                    const int k = itt >> 1;           // 1..3 here
                    st = (k == 1) ? cin1 : (k == 2) ? cin2 : cin3;
                }
                scan_xs_tile(Xs, tid, c_s, st);
            }
        }

        // ---- coalesced store phase: 2 rounds x 16 rows ----
        #pragma unroll
        for (int r = 0; r < 2; ++r) {
            const int m = r * 16 + hrow;
            bf16x8 ev = *(const bf16x8*)((const char*)Es + m * 512 + (((nc * 2) ^ (hrow << 2)) * 8));
            const size_t gidx = (mt0 + m) * 256 + nc * 8;
            if (MODE == 0) {
                *(bf16x8*)((__bf16*)Cout + gidx) = ev;
            } else if (MODE == 1) {
                bf16x8 xv = *(const bf16x8*)&xn_in[gidx];
                f32x4 d0 = *(const f32x4*)&dvec[nc * 8];
                f32x4 d1 = *(const f32x4*)&dvec[nc * 8 + 4];
                bf16x8 pk;
                #pragma unroll
                for (int j = 0; j < 8; ++j) {
                    float dj = (j < 4) ? d0[j] : d1[j - 4];
                    float t = (float)ev[j] + dj * (float)xv[j];
                    // gelu(t) = t * sigmoid(1.5957691*(t + 0.044715 t^3))
                    float q = t + 0.044715f * t * t * t;
                    float e = __expf(-1.5957691216057308f * q);
                    pk[j] = (__bf16)(t * __builtin_amdgcn_rcpf(1.f + e));
                }
                *(bf16x8*)((__bf16*)Cout + gidx) = pk;
            } else {
                f32x4 x0 = *(const f32x4*)&xres[gidx];
                f32x4 x1 = *(const f32x4*)&xres[gidx + 4];
                f32x4 b0 = *(const f32x4*)&bias[nc * 8];
                f32x4 b1 = *(const f32x4*)&bias[nc * 8 + 4];
                f32x4 y0, y1;
                #pragma unroll
                for (int j = 0; j < 4; ++j) {
                    y0[j] = x0[j] + (float)ev[j]     + b0[j];
                    y1[j] = x1[j] + (float)ev[j + 4] + b1[j];
                }
                *(f32x4*)((float*)Cout + gidx)     = y0;
                *(f32x4*)((float*)Cout + gidx + 4) = y1;
            }
        }

        // ---- MODE0: fused per-chunk carry over Es(it) (read-only, reg carry) ----
        if constexpr (MODE == 0) {
            if (tid < 256) {
                if ((it & 1) == 0) stc = (it == 0 && chb == 0) ? s0v : 0.f;
                scan_es_carry(Es, tid, c_s, stc);
                if ((it & 1) == 1)
                    carry[((size_t)bb * 64 + (chb + (it >> 1))) * 256 + tid] = stc;
            }
        }

        // ---- MODE1: make scanned Xs(it+1) visible to all waves ----
        if constexpr (MODE == 1) {
            if (it + 1 < NT) __syncthreads();   // S
        }
    }
}

// ---------------- scan pass 2: prefix over chunk carries ----------------
__global__ __launch_bounds__(256) void scan_prefix(float* carry, const float* __restrict__ cL,
                            float* __restrict__ fs_out) {
    int b = blockIdx.x, s = threadIdx.x;
    float cl = cL[s];
    float P = 0.f;
    for (int j = 0; j < NCHUNK; ++j) {
        int idx = (b * NCHUNK + j) * SS + s;
        P = cl * P + carry[idx];
        carry[idx] = P;     // inclusive prefix = state at end of chunk j
    }
    fs_out[b * SS + s] = P; // final_state (t = T-1)
}

extern "C" void kernel_launch(void* const* d_in, const int* in_sizes, int n_in,
                              void* d_out, int out_size, void* d_ws, size_t ws_size,
                              hipStream_t stream) {
    const float* x      = (const float*)d_in[0];
    const float* state0 = (const float*)d_in[1];
    const float* w1     = (const float*)d_in[2];   // in_to_state [S,H]
    const float* w2     = (const float*)d_in[3];   // state_to_hidden [H,S]
    const float* direct = (const float*)d_in[4];
    const float* a_diag = (const float*)d_in[5];
    const float* g_diag = (const float*)d_in[6];
    const float* dt     = (const float*)d_in[7];
    const float* norm_w = (const float*)d_in[8];
    const float* norm_b = (const float*)d_in[9];
    const float* w3     = (const float*)d_in[10];  // out_w [H,H]
    const float* out_b  = (const float*)d_in[11];

    char* ws = (char*)d_ws;
    const size_t MH2 = (size_t)MTOT * HH * 2;      // 67108864
    __bf16* xn    = (__bf16*)(ws);                  // [M,H] bf16 (later holds mixed)
    __bf16* u     = (__bf16*)(ws + MH2);            // [M,S] bf16
    __bf16* w1b   = (__bf16*)(ws + 2*MH2);
    __bf16* w2b   = (__bf16*)(ws + 2*MH2 + 131072);
    __bf16* w3b   = (__bf16*)(ws + 2*MH2 + 262144);
    float*  coeff = (float*)(ws + 2*MH2 + 393216);
    float*  cL    = (float*)(ws + 2*MH2 + 394240);
    float*  carry = (float*)(ws + 2*MH2 + 395264);  // [B, NCHUNK, S] f32 = 2MB

    float* y_out  = (float*)d_out;
    float* fs_out = (float*)d_out + (size_t)MTOT * HH;

    prep_kernel<<<256, 256, 0, stream>>>(w1, w2, w3, w1b, w2b, w3b,
                                         a_diag, g_diag, dt, coeff, cL);
    ln_kernel<<<MTOT/4, 256, 0, stream>>>(x, norm_w, norm_b, xn);
    gemm_kernel<0><<<512, 512, 0, stream>>>(w1b, xn, u, nullptr, nullptr, nullptr, nullptr,
                                            coeff, state0, carry);
    scan_prefix<<<BB, 256, 0, stream>>>(carry, cL, fs_out);
    gemm_kernel<1><<<512, 512, 0, stream>>>(w2b, u, xn, xn, direct, nullptr, nullptr,
                                            coeff, state0, carry);
    gemm_kernel<2><<<512, 512, 0, stream>>>(w3b, xn, y_out, nullptr, nullptr, x, out_b,
                                            nullptr, nullptr, nullptr);
}